// Round 1
// baseline (421.601 us; speedup 1.0000x reference)
//
#include <hip/hip_runtime.h>
#include <math.h>

#define Bn 8
#define Hn 128
#define Pn 128
#define Ln 4096
#define LF 2049           // Ln/2 + 1
#define NROWS (Bn*Hn)     // 1024
#define TL 4              // l-bins per mixfreq block

// ---------------------------------------------------------------------------
// prep kernels: fold the H-axis FFTs into the weight matrices.
//   F[q,h]    = exp(-2*pi*i*q*h/128)        (forward DFT along H)
//   Finv[h,q] = exp(+2*pi*i*h*q/128)/128    (inverse DFT along H)
//   B2t[h][p] = (B_bar @ F)[p][h]
//   C2t[p][h] = (Finv @ C)[h][p]
//   E[a][q]   = (D @ F)[a][q]     (temp)
//   D2t[q][h] = (Finv @ E)[h][q]
// ---------------------------------------------------------------------------

__global__ void prep_B2t_k(const float* __restrict__ B_ri, float2* __restrict__ B2t) {
    int idx = blockIdx.x * blockDim.x + threadIdx.x;   // h*128 + p
    int h = idx >> 7, p = idx & 127;
    float sr = 0.f, si = 0.f;
    for (int q = 0; q < 128; ++q) {
        float br = B_ri[(p * 128 + q) * 2 + 0];
        float bi = B_ri[(p * 128 + q) * 2 + 1];
        float ang = -3.14159265358979f * (float)((q * h) & 127) / 64.0f;
        float sw, cw; __sincosf(ang, &sw, &cw);
        sr += br * cw - bi * sw;
        si += br * sw + bi * cw;
    }
    B2t[idx] = make_float2(sr, si);
}

__global__ void prep_C2t_k(const float* __restrict__ C_ri, float2* __restrict__ C2t) {
    int idx = blockIdx.x * blockDim.x + threadIdx.x;   // p*128 + h
    int p = idx >> 7, h = idx & 127;
    float sr = 0.f, si = 0.f;
    for (int h2 = 0; h2 < 128; ++h2) {
        float cr = C_ri[(h2 * 128 + p) * 2 + 0];
        float ci = C_ri[(h2 * 128 + p) * 2 + 1];
        float ang = 3.14159265358979f * (float)((h * h2) & 127) / 64.0f;
        float sw, cw; __sincosf(ang, &sw, &cw);
        sr += cr * cw - ci * sw;
        si += cr * sw + ci * cw;
    }
    C2t[idx] = make_float2(sr * (1.0f / 128.0f), si * (1.0f / 128.0f));
}

__global__ void prep_E_k(const float* __restrict__ D_ri, float2* __restrict__ E) {
    int idx = blockIdx.x * blockDim.x + threadIdx.x;   // a*128 + q
    int a = idx >> 7, q = idx & 127;
    float sr = 0.f, si = 0.f;
    for (int c = 0; c < 128; ++c) {
        float dr = D_ri[(a * 128 + c) * 2 + 0];
        float di = D_ri[(a * 128 + c) * 2 + 1];
        float ang = -3.14159265358979f * (float)((c * q) & 127) / 64.0f;
        float sw, cw; __sincosf(ang, &sw, &cw);
        sr += dr * cw - di * sw;
        si += dr * sw + di * cw;
    }
    E[idx] = make_float2(sr, si);
}

__global__ void prep_D2t_k(const float2* __restrict__ E, float2* __restrict__ D2t) {
    int idx = blockIdx.x * blockDim.x + threadIdx.x;   // q*128 + h
    int q = idx >> 7, h = idx & 127;
    float sr = 0.f, si = 0.f;
    for (int a = 0; a < 128; ++a) {
        float2 e = E[a * 128 + q];
        float ang = 3.14159265358979f * (float)((h * a) & 127) / 64.0f;
        float sw, cw; __sincosf(ang, &sw, &cw);
        sr += e.x * cw - e.y * sw;
        si += e.x * sw + e.y * cw;
    }
    D2t[idx] = make_float2(sr * (1.0f / 128.0f), si * (1.0f / 128.0f));
}

// ---------------------------------------------------------------------------
// 4096-pt Stockham radix-2 FFT in LDS. SIGN=-1 forward, +1 inverse (unnormalized).
// 256 threads, 8 butterflies/thread/stage, 12 stages. Result ends in bufA.
// Caller must __syncthreads() after filling bufA, before calling.
// ---------------------------------------------------------------------------
template <int SIGN>
__device__ __forceinline__ void stockham4096(float2* bufA, float2* bufB) {
    const int tid = threadIdx.x;
    float2* src = bufA;
    float2* dst = bufB;
    for (int st = 0; st < 12; ++st) {
        const int n = 4096 >> st;
        const int m = n >> 1;
        const int ls = st;                  // log2(s)
        const float invn = 1.0f / (float)n;
        for (int r = 0; r < 8; ++r) {
            int k = tid + (r << 8);         // 0..2047
            int q = k & ((1 << ls) - 1);
            int p = k >> ls;                // < m
            float2 a = src[q + (p << ls)];
            float2 b = src[q + ((p + m) << ls)];
            float ang = (float)SIGN * 6.28318530717959f * (float)p * invn;
            float sw, cw; __sincosf(ang, &sw, &cw);
            float dx = a.x - b.x, dy = a.y - b.y;
            int o = q + (p << (ls + 1));
            dst[o] = make_float2(a.x + b.x, a.y + b.y);
            dst[o + (1 << ls)] = make_float2(dx * cw - dy * sw, dx * sw + dy * cw);
        }
        __syncthreads();
        float2* t = src; src = dst; dst = t;
    }
    // 12 swaps -> result back in bufA
}

__global__ __launch_bounds__(256) void rfft_rows_k(const float* __restrict__ u,
                                                   float2* __restrict__ Uhat) {
    __shared__ float2 bufA[4096];
    __shared__ float2 bufB[4096];
    const int row = blockIdx.x;
    const int tid = threadIdx.x;
    const float* up = u + (size_t)row * Ln;
    for (int i = tid; i < Ln; i += 256) bufA[i] = make_float2(up[i], 0.f);
    __syncthreads();
    stockham4096<-1>(bufA, bufB);
    float2* op = Uhat + (size_t)row * LF;
    for (int l = tid; l < LF; l += 256) op[l] = bufA[l];
}

__global__ __launch_bounds__(256) void irfft_gelu_k(const float2* __restrict__ Uhat,
                                                    float* __restrict__ out) {
    __shared__ float2 bufA[4096];
    __shared__ float2 bufB[4096];
    const int row = blockIdx.x;
    const int tid = threadIdx.x;
    const float2* wp = Uhat + (size_t)row * LF;
    for (int l = tid; l < LF; l += 256) {
        float2 v = wp[l];
        bufA[l] = v;
        if (l >= 1 && l <= Ln / 2 - 1) bufA[Ln - l] = make_float2(v.x, -v.y);
    }
    __syncthreads();
    stockham4096<1>(bufA, bufB);
    float* op = out + (size_t)row * Ln;
    for (int i = tid; i < Ln; i += 256) {
        float y = bufA[i].x * (1.0f / (float)Ln);
        op[i] = 0.5f * y * (1.0f + erff(y * 0.70710678118655f));
    }
}

// ---------------------------------------------------------------------------
// mixfreq: per frequency bin l, along original-H axis:
//   W[b,:,l] = C2 * diag(mid(:,l)) * B2 * U[b,:,l] + D2 * U[b,:,l]
// In-place on Uhat. One block handles TL=4 consecutive bins for all (b,h).
// mid[p,l] = 1 / (i*2*pi*l/L - Lam_bar[p]).
// ---------------------------------------------------------------------------
__global__ __launch_bounds__(256) void mixfreq_k(float2* __restrict__ Uhat,
                                                 const float2* __restrict__ B2t,
                                                 const float2* __restrict__ C2t,
                                                 const float2* __restrict__ D2t,
                                                 const float* __restrict__ Lam) {
    __shared__ float2 Us[NROWS][TL];   // 32 KB
    __shared__ float2 Tm[NROWS];       // 8 KB  (b*128+p)
    __shared__ float2 lam[Pn];         // 1 KB
    const int tid = threadIdx.x;
    const int l0 = blockIdx.x * TL;

    if (tid < Pn) lam[tid] = make_float2(Lam[tid * 2 + 0], Lam[tid * 2 + 1]);
    for (int i = tid; i < NROWS * TL; i += 256) {
        int r = i >> 2, j = i & (TL - 1);
        int l = l0 + j;
        Us[r][j] = (l < LF) ? Uhat[(size_t)r * LF + l] : make_float2(0.f, 0.f);
    }
    __syncthreads();

    const int pp = tid & 127;   // p (phase 1) / h (phase 2)
    const int b0 = tid >> 7;    // 0 or 1; b = b0 + 2r

    for (int j = 0; j < TL; ++j) {
        const int l = l0 + j;
        // ---- T[b][p] = sum_h B2t[h][p] * Us[b*128+h][j] ----
        float2 acc[4];
        #pragma unroll
        for (int r = 0; r < 4; ++r) acc[r] = make_float2(0.f, 0.f);
        for (int hh = 0; hh < 128; ++hh) {
            float2 w = B2t[hh * 128 + pp];
            #pragma unroll
            for (int r = 0; r < 4; ++r) {
                float2 uv = Us[(b0 + 2 * r) * 128 + hh][j];
                acc[r].x += w.x * uv.x - w.y * uv.y;
                acc[r].y += w.x * uv.y + w.y * uv.x;
            }
        }
        // ---- mid(p, l) multiply ----
        float wl = 3.14159265358979f * (float)l / 2048.0f;   // 2*pi*l/4096
        float dr = -lam[pp].x;
        float di = wl - lam[pp].y;
        float inv = 1.0f / (dr * dr + di * di);
        float mr = dr * inv, mi = -di * inv;
        #pragma unroll
        for (int r = 0; r < 4; ++r) {
            float2 t;
            t.x = acc[r].x * mr - acc[r].y * mi;
            t.y = acc[r].x * mi + acc[r].y * mr;
            Tm[(b0 + 2 * r) * 128 + pp] = t;
        }
        __syncthreads();   // Tm visible
        // ---- W[b][h] = sum_p C2t[p][h]*Tm[b,p] + sum_q D2t[q][h]*Us[b*128+q][j] ----
        float2 wacc[4];
        #pragma unroll
        for (int r = 0; r < 4; ++r) wacc[r] = make_float2(0.f, 0.f);
        for (int p = 0; p < 128; ++p) {
            float2 c = C2t[p * 128 + pp];
            #pragma unroll
            for (int r = 0; r < 4; ++r) {
                float2 t = Tm[(b0 + 2 * r) * 128 + p];
                wacc[r].x += c.x * t.x - c.y * t.y;
                wacc[r].y += c.x * t.y + c.y * t.x;
            }
        }
        for (int q = 0; q < 128; ++q) {
            float2 d = D2t[q * 128 + pp];
            #pragma unroll
            for (int r = 0; r < 4; ++r) {
                float2 uv = Us[(b0 + 2 * r) * 128 + q][j];
                wacc[r].x += d.x * uv.x - d.y * uv.y;
                wacc[r].y += d.x * uv.y + d.y * uv.x;
            }
        }
        __syncthreads();   // all reads of Us[.][j] and Tm complete
        #pragma unroll
        for (int r = 0; r < 4; ++r) Us[(b0 + 2 * r) * 128 + pp][j] = wacc[r];
    }
    __syncthreads();
    for (int i = tid; i < NROWS * TL; i += 256) {
        int r = i >> 2, j = i & (TL - 1);
        int l = l0 + j;
        if (l < LF) Uhat[(size_t)r * LF + l] = Us[r][j];
    }
}

// ---------------------------------------------------------------------------
extern "C" void kernel_launch(void* const* d_in, const int* in_sizes, int n_in,
                              void* d_out, int out_size, void* d_ws, size_t ws_size,
                              hipStream_t stream) {
    const float* u    = (const float*)d_in[0];   // (B,H,L)
    const float* C_ri = (const float*)d_in[1];   // (H,P,2)
    const float* D_ri = (const float*)d_in[2];   // (H,H,2)
    const float* B_ri = (const float*)d_in[3];   // (P,H,2)
    const float* Lam  = (const float*)d_in[4];   // (P,2)
    float* out = (float*)d_out;

    float2* Uhat = (float2*)d_ws;                  // NROWS*LF float2 = 16.0 MiB
    float2* B2t  = Uhat + (size_t)NROWS * LF;
    float2* C2t  = B2t + 128 * 128;
    float2* D2t  = C2t + 128 * 128;
    float2* Em   = D2t + 128 * 128;

    prep_B2t_k<<<64, 256, 0, stream>>>(B_ri, B2t);
    prep_C2t_k<<<64, 256, 0, stream>>>(C_ri, C2t);
    prep_E_k  <<<64, 256, 0, stream>>>(D_ri, Em);
    prep_D2t_k<<<64, 256, 0, stream>>>(Em, D2t);

    rfft_rows_k<<<NROWS, 256, 0, stream>>>(u, Uhat);
    mixfreq_k<<<(LF + TL - 1) / TL, 256, 0, stream>>>(Uhat, B2t, C2t, D2t, Lam);
    irfft_gelu_k<<<NROWS, 256, 0, stream>>>(Uhat, out);
}